// Round 4
// baseline (93.981 us; speedup 1.0000x reference)
//
#include <hip/hip_runtime.h>

#define EPSF 0.01f
#define THREADS 256
#define ITEMS 32
#define TILE (THREADS * ITEMS)  // 8192 elements per tile
#define TPB 2                   // tiles per block -> chunk = 16384

typedef unsigned long long u64;
typedef unsigned int u32;

// Per-category change scalars, exactly as the reference computes them.
// jnp.clip(x, lo, hi) == min(max(x, lo), hi)
__device__ __forceinline__ void load_changes(const float* bd, const float* de,
                                             const float* sa, const float* in,
                                             const float* bi, float ch[5]) {
    float vbd = *bd, vd = *de, vs = *sa, vi = *in, vbi = *bi;
    ch[0] = fminf(vbd, fminf(0.0f, vd) - EPSF);
    ch[1] = fminf(fmaxf(vd, vbd + EPSF), 0.0f - EPSF);
    ch[2] = fminf(fmaxf(vs, vd + EPSF), vi - EPSF);
    ch[3] = fminf(fmaxf(vi, 0.0f + EPSF), vbi - EPSF);
    ch[4] = fmaxf(vbi, fmaxf(0.0f, vi) + EPSF);
}

// codes are 0..4 (category-1); cmp+cndmask chain, no runtime-indexed array.
__device__ __forceinline__ float selc(u32 v, float c0, float c1, float c2,
                                      float c3, float c4) {
    return (v == 0) ? c0 : (v == 1) ? c1 : (v == 2) ? c2 : (v == 3) ? c3 : c4;
}

// Pass 1: read ann once; emit packed 4-bit codes (16.8 MB) + exact per-block
// category counts (12-bit packed per-thread fields; <=64 per field).
// Counts stored transposed bcT[c*nb+b] so pass 2's predecessor sum coalesces.
__global__ __launch_bounds__(THREADS) void k_pack(const int* __restrict__ ann,
                                                  u32* __restrict__ codes,
                                                  int* __restrict__ bcT,
                                                  long long n, long long chunk,
                                                  int nb) {
    long long start = (long long)blockIdx.x * chunk;
    u64 pk = 0ull;

    for (int t = 0; t < TPB; ++t) {
        long long base = start + (long long)t * TILE;
        if (base >= n) break;  // uniform per block
        long long i0 = base + (long long)threadIdx.x * ITEMS;
        u32 w0 = 0, w1 = 0, w2 = 0, w3 = 0;
        if (base + TILE <= n) {
            const int4* p = reinterpret_cast<const int4*>(ann + i0);
#pragma unroll
            for (int k = 0; k < 8; ++k) {
                int4 a = p[k];
                u32 cx = (u32)(a.x - 1), cy = (u32)(a.y - 1);
                u32 cz = (u32)(a.z - 1), cw = (u32)(a.w - 1);
                pk += (1ull << (cx * 12)) + (1ull << (cy * 12)) +
                      (1ull << (cz * 12)) + (1ull << (cw * 12));
                u32 nib = cx | (cy << 4) | (cz << 8) | (cw << 12);
                u32 sh = (k & 1) * 16;
                if (k < 2) w0 |= nib << sh;
                else if (k < 4) w1 |= nib << sh;
                else if (k < 6) w2 |= nib << sh;
                else w3 |= nib << sh;
            }
        } else {
#pragma unroll
            for (int j = 0; j < ITEMS; ++j) {
                long long i = i0 + j;
                u32 c = 0;
                if (i < n) {
                    c = (u32)(ann[i] - 1);
                    pk += (1ull << (c * 12));
                }
                u32 sh = (j & 7) * 4;
                if (j < 8) w0 |= c << sh;
                else if (j < 16) w1 |= c << sh;
                else if (j < 24) w2 |= c << sh;
                else w3 |= c << sh;
            }
        }
        if (i0 < n)
            *reinterpret_cast<uint4*>(codes + (i0 >> 3)) =
                make_uint4(w0, w1, w2, w3);
    }

    int cnt[5];
#pragma unroll
    for (int c = 0; c < 5; ++c) cnt[c] = (int)((pk >> (c * 12)) & 0xFFFull);
    const int lane = threadIdx.x & 63, wv = threadIdx.x >> 6;
#pragma unroll
    for (int c = 0; c < 5; ++c) {
        int x = cnt[c];
#pragma unroll
        for (int off = 32; off > 0; off >>= 1) x += __shfl_down(x, off, 64);
        cnt[c] = x;  // lane 0 holds wave total
    }
    __shared__ int sred[THREADS / 64][5];
    if (lane == 0) {
#pragma unroll
        for (int c = 0; c < 5; ++c) sred[wv][c] = cnt[c];
    }
    __syncthreads();
    if (threadIdx.x == 0) {
#pragma unroll
        for (int c = 0; c < 5; ++c)
            bcT[c * nb + blockIdx.x] =
                sred[0][c] + sred[1][c] + sred[2][c] + sred[3][c];
    }
}

// Pass 2: redundant predecessor-sum of counts (L2-resident, no serialization)
// -> exact float base; then decode codes + block scan + emit. Exclusive-prefix
// form keeps every float4 store aligned; out[0]=origin falls out naturally.
__global__ __launch_bounds__(THREADS) void k_emit(
    const u32* __restrict__ codes, const int* __restrict__ bcT,
    float* __restrict__ out, long long n, long long chunk, int nb,
    const float* org, const float* bd, const float* de, const float* sa,
    const float* in, const float* bi) {
    float ch[5];
    load_changes(bd, de, sa, in, bi, ch);
    const float c0 = ch[0], c1 = ch[1], c2 = ch[2], c3 = ch[3], c4 = ch[4];

    __shared__ int sred[THREADS / 64][5];
    __shared__ float wsum[THREADS / 64];
    __shared__ float s_base;

    const int vbid = blockIdx.x;
    const int lane = threadIdx.x & 63, wv = threadIdx.x >> 6;

    // Phase A: base = org + sum_c (#cat_c before my chunk) * ch_c  (exact ints)
    int pc[5];
#pragma unroll
    for (int c = 0; c < 5; ++c) {
        int s = 0;
        for (int j = threadIdx.x; j < vbid; j += THREADS) s += bcT[c * nb + j];
#pragma unroll
        for (int off = 32; off > 0; off >>= 1) s += __shfl_down(s, off, 64);
        pc[c] = s;
    }
    if (lane == 0) {
#pragma unroll
        for (int c = 0; c < 5; ++c) sred[wv][c] = pc[c];
    }
    __syncthreads();
    if (threadIdx.x == 0) {
        double acc = (double)(*org);
#pragma unroll
        for (int c = 0; c < 5; ++c) {
            int tot = sred[0][c] + sred[1][c] + sred[2][c] + sred[3][c];
            acc += (double)tot * (double)ch[c];
        }
        s_base = (float)acc;
    }
    __syncthreads();

    long long start = (long long)vbid * chunk;
    long long end = start + chunk;
    if (end > n) end = n;
    float running = s_base;

    for (int t = 0; t < TPB; ++t) {
        long long base = start + (long long)t * TILE;
        if (base >= n) break;  // uniform per block
        long long i0 = base + (long long)threadIdx.x * ITEMS;
        const bool full = (base + TILE <= n);

        uint4 cv = (i0 < n) ? *reinterpret_cast<const uint4*>(codes + (i0 >> 3))
                            : make_uint4(0, 0, 0, 0);
        u32 cwa[4] = {cv.x, cv.y, cv.z, cv.w};

        // local sum (decode pass 1)
        float lsum = 0.0f;
        if (full) {
#pragma unroll
            for (int j = 0; j < ITEMS; ++j)
                lsum += selc((cwa[j >> 3] >> ((j & 7) * 4)) & 0xF, c0, c1, c2,
                             c3, c4);
        } else {
#pragma unroll
            for (int j = 0; j < ITEMS; ++j)
                if (i0 + j < n)
                    lsum += selc((cwa[j >> 3] >> ((j & 7) * 4)) & 0xF, c0, c1,
                                 c2, c3, c4);
        }

        // block exclusive scan of per-thread sums
        float x = lsum;
#pragma unroll
        for (int off = 1; off < 64; off <<= 1) {
            float y = __shfl_up(x, off, 64);
            if (lane >= off) x += y;
        }
        if (lane == 63) wsum[wv] = x;
        __syncthreads();
        float w0 = wsum[0], w1 = wsum[1], w2 = wsum[2], w3 = wsum[3];
        float waveOff = (wv > 0 ? w0 : 0.0f) + (wv > 1 ? w1 : 0.0f) +
                        (wv > 2 ? w2 : 0.0f);
        float total = w0 + w1 + w2 + w3;
        __syncthreads();  // wsum reused next tile

        // emit (decode pass 2), exclusive prefix
        float acc = running + waveOff + (x - lsum);
        if (full) {
            float4* q = reinterpret_cast<float4*>(out + i0);
#pragma unroll
            for (int g = 0; g < 8; ++g) {
                float4 f;
                f.x = acc;
                acc += selc((cwa[g >> 1] >> (((4 * g + 0) & 7) * 4)) & 0xF, c0, c1, c2, c3, c4);
                f.y = acc;
                acc += selc((cwa[g >> 1] >> (((4 * g + 1) & 7) * 4)) & 0xF, c0, c1, c2, c3, c4);
                f.z = acc;
                acc += selc((cwa[g >> 1] >> (((4 * g + 2) & 7) * 4)) & 0xF, c0, c1, c2, c3, c4);
                f.w = acc;
                acc += selc((cwa[g >> 1] >> (((4 * g + 3) & 7) * 4)) & 0xF, c0, c1, c2, c3, c4);
                q[g] = f;
            }
        } else {
#pragma unroll
            for (int j = 0; j < ITEMS; ++j) {
                if (i0 + j < n) {
                    out[i0 + j] = acc;
                    acc += selc((cwa[j >> 3] >> ((j & 7) * 4)) & 0xF, c0, c1,
                                c2, c3, c4);
                }
            }
        }
        running += total;
    }
    if (end == n && start < n && threadIdx.x == 0) out[n] = running;
}

extern "C" void kernel_launch(void* const* d_in, const int* in_sizes, int n_in,
                              void* d_out, int out_size, void* d_ws, size_t ws_size,
                              hipStream_t stream) {
    const int* ann = (const int*)d_in[0];
    const float* org = (const float*)d_in[1];
    const float* bd = (const float*)d_in[2];
    const float* de = (const float*)d_in[3];
    const float* sa = (const float*)d_in[4];
    const float* in = (const float*)d_in[5];
    const float* bi = (const float*)d_in[6];
    float* out = (float*)d_out;

    long long n = (long long)in_sizes[0];
    long long chunk = (long long)TPB * TILE;      // 16384
    int nb = (int)((n + chunk - 1) / chunk);      // 2048 for N=2^25
    if (nb < 1) nb = 1;

    // ws layout: bcT (nb*5 ints) | codes (ceil(n/8) u32, 256B-aligned)
    int* bcT = (int*)d_ws;
    size_t bct_bytes = ((size_t)nb * 5 * sizeof(int) + 255) & ~(size_t)255;
    u32* codes = (u32*)((char*)d_ws + bct_bytes);

    k_pack<<<nb, THREADS, 0, stream>>>(ann, codes, bcT, n, chunk, nb);
    k_emit<<<nb, THREADS, 0, stream>>>(codes, bcT, out, n, chunk, nb, org, bd,
                                       de, sa, in, bi);
}